// Round 10
// baseline (361.908 us; speedup 1.0000x reference)
//
#include <hip/hip_runtime.h>
#include <stdint.h>

#define B_ 16
#define T_ 4096
#define C_ 64
#define H_ 128
#define BQ 128
#define BK 64

typedef _Float16 f16;
typedef __attribute__((ext_vector_type(8))) _Float16 half8;   // 4 VGPRs (16x16x32 A/B)
typedef __attribute__((ext_vector_type(4))) _Float16 half4;   // 2 VGPRs
typedef __attribute__((ext_vector_type(2))) _Float16 half2v;  // 1 VGPR
typedef __attribute__((ext_vector_type(4))) float   floatx4;  // MFMA C/D frag

__device__ __forceinline__ f16 f2h(float f) { return (f16)f; }

__device__ __forceinline__ float fexp2(float x) {
#if __has_builtin(__builtin_amdgcn_exp2f)
    return __builtin_amdgcn_exp2f(x);
#else
    return exp2f(x);
#endif
}

// packed f32x2 -> f16x2 (single v_cvt_pkrtz_f16_f32)
__device__ __forceinline__ half2v pkrtz(float a, float b) {
    return __builtin_bit_cast(half2v, __builtin_amdgcn_cvt_pkrtz(a, b));
}

// async global->LDS, 16 B per lane, dest = wave-uniform base + lane*16
__device__ __forceinline__ void async_cp16(const void* g, void* l) {
    __builtin_amdgcn_global_load_lds(
        (const __attribute__((address_space(1))) unsigned int*)g,
        (__attribute__((address_space(3))) unsigned int*)l, 16, 0, 0);
}

// q is pre-scaled by scale*log2(e) at projection time (attn does exp2(S) raw)
#define QSCALE 0.18033688011112042f   // 0.125 * log2(e)

// ---------------------------------------------------------------------------
// W prep: Wk/Wq/Wv fp32 [C][H] -> f16 W^T [m][H][C], done ONCE.
// Grid (3 m, 16 h-groups) = 48 blocks.
// ---------------------------------------------------------------------------
__global__ __launch_bounds__(256) void wprep_kernel(
    const float* __restrict__ Wk, const float* __restrict__ Wq,
    const float* __restrict__ Wv, f16* __restrict__ wt)
{
    const int m  = blockIdx.x;
    const int hg = blockIdx.y;
    const float* W = (m == 0) ? Wk : (m == 1) ? Wq : Wv;
    f16* o = wt + m * (C_ * H_);
    #pragma unroll
    for (int it = 0; it < 2; ++it) {
        int idx = hg * 512 + it * 256 + threadIdx.x;  // idx = h*64 + c
        int h = idx >> 6, c = idx & 63;
        o[idx] = f2h(W[c * H_ + h]);                  // strided 4B reads, L2-resident
    }
}

// ---------------------------------------------------------------------------
// MFMA projections: q,k -> f16 [B][T][H]; v -> f16 vt[B][H][T'].
// vt's t-order is PERMUTED within each 64-t chunk so attn's PV operand is one
// contiguous 16-B granule per lane:
//   position p = 8g+u  holds  t-offset k = 32*g2 | 16*u2 | 8*g1 | 4*g0 | u1u0
// (g = granule 0..7, u = 0..7). Then granule g = 4*sp32 + quad is exactly the
// 8 k-values lane(quad) needs for PV tile-pair sp32 -> one global b128 load.
// q (m==1) is multiplied by QSCALE before the f16 store.
// ---------------------------------------------------------------------------
#define QKS 132   // q/k scratch stride (f16)
#define VTS 72    // vt scratch stride (f16)

__global__ __launch_bounds__(256) void proj_kernel(
    const float* __restrict__ x, const f16* __restrict__ wt,
    f16* __restrict__ qo, f16* __restrict__ ko, f16* __restrict__ vto)
{
    __shared__ __align__(16) char smem[20480];
    f16* Sw  = (f16*)smem;                          // per-wave [16][QKS] transpose scratch
    f16* vtl = (f16*)smem;                          // [128 h][VTS]  18432 B (aliases Sw)

    const int tid  = threadIdx.x;
    const int wave = tid >> 6;
    const int lane = tid & 63;
    const int col  = lane & 15;
    const int quad = lane >> 4;
    const int b    = blockIdx.x >> 6;
    const int t0   = (blockIdx.x & 63) * 64;

    // A-fragments: x rows t0+wave*16+col, K=64 in 2 ks-steps (fp32 -> f16)
    half8 ax[2];
    {
        const float* xr = x + ((size_t)(b * T_ + t0 + wave * 16 + col)) * C_ + quad * 8;
        #pragma unroll
        for (int ks = 0; ks < 2; ++ks) {
            float4 a0 = *(const float4*)(xr + ks * 32);
            float4 a1 = *(const float4*)(xr + ks * 32 + 4);
            ax[ks] = half8{f2h(a0.x), f2h(a0.y), f2h(a0.z), f2h(a0.w),
                           f2h(a1.x), f2h(a1.y), f2h(a1.z), f2h(a1.w)};
        }
    }

    #pragma unroll
    for (int m = 0; m < 3; ++m) {
        const f16* Wm = wt + m * (C_ * H_);
        const float sc = (m == 1) ? QSCALE : 1.0f;   // fold attn scale into q

        floatx4 acc[8];
        #pragma unroll
        for (int nt = 0; nt < 8; ++nt) { acc[nt][0]=0.f; acc[nt][1]=0.f; acc[nt][2]=0.f; acc[nt][3]=0.f; }
        #pragma unroll
        for (int nt = 0; nt < 8; ++nt)
            #pragma unroll
            for (int ks = 0; ks < 2; ++ks) {
                half8 bf = *(const half8*)(Wm + (nt * 16 + col) * C_ + ks * 32 + quad * 8);
                acc[nt] = __builtin_amdgcn_mfma_f32_16x16x32_f16(ax[ks], bf, acc[nt], 0, 0, 0);
            }

        if (m < 2) {
            // wave-private scratch: DS ops of one wave execute in order -> no barrier
            f16* S = Sw + wave * 16 * QKS;
            #pragma unroll
            for (int nt = 0; nt < 8; ++nt)
                #pragma unroll
                for (int r = 0; r < 4; ++r)
                    S[(quad * 4 + r) * QKS + nt * 16 + col] = f2h(acc[nt][r] * sc);
            f16* o = (m == 0) ? ko : qo;
            int rw = lane >> 2;
            #pragma unroll
            for (int p = 0; p < 4; ++p) {
                int ck = (lane & 3) + p * 4;
                half8 d = *(const half8*)&S[rw * QKS + ck * 8];
                *(half8*)(o + ((size_t)(b * T_ + t0 + wave * 16 + rw)) * H_ + ck * 8) = d;
            }
        } else {
            __syncthreads();   // all waves' q-scratch reads done; vtl spans whole smem
            #pragma unroll
            for (int nt = 0; nt < 8; ++nt)
                #pragma unroll
                for (int r = 0; r < 4; ++r)
                    vtl[(nt * 16 + col) * VTS + wave * 16 + quad * 4 + r] = f2h(acc[nt][r]);
            __syncthreads();
            // permuted store: source granule gs (t = 8gs..8gs+7) splits into two
            // 8-B halves at positions (G, u4) and (G+1, u4), G = 4*gs2 + 2*gs0,
            // u4 = 4*gs1  (see layout comment above).
            int h  = tid >> 1;
            int sg = (tid & 1) * 32;
            f16* drow = vto + ((size_t)(b * H_ + h)) * T_ + t0;
            const int4* src = (const int4*)&vtl[h * VTS + sg];
            #pragma unroll
            for (int i = 0; i < 4; ++i) {
                int gs = (sg >> 3) + i;
                int G  = ((gs >> 2) << 2) | ((gs & 1) << 1);
                int u4 = ((gs >> 1) & 1) << 2;
                int4 v = src[i];
                *(int2*)(drow + (G + 0) * 8 + u4) = make_int2(v.x, v.y);
                *(int2*)(drow + (G + 1) * 8 + u4) = make_int2(v.z, v.w);
            }
        }
    }
}

// ---------------------------------------------------------------------------
// Flash attention. Grid (16 b, 32 q): x = b -> all 32 q-blocks of a batch on
// one XCD, K/V served from its L2 (round 9: FETCH 139->24.6 MB).
// DS-pipe diet (round 9: DS was 58% of CU cycles, the top pipe — all 4 waves
// re-read identical K AND V fragments from LDS): V now loads DIRECTLY from
// global (L2-hot) into registers — the permuted vt layout makes each lane's
// PV operand one contiguous 16-B granule -> single global_load_dwordx4.
// Deletes 16 ds_read_b128 + 16 LDS staging writes per wave per chunk (~50%
// of DS traffic). va0 issued before QK (~800 cyc cover), va1 before softmax.
// K stays LDS-staged (4x dedupe), double-buffered; ONE barrier per chunk;
// chunk loop unrolled x2 for compile-time buffer index.
// ---------------------------------------------------------------------------
__global__ __launch_bounds__(256, 2) void attn_kernel(
    const f16* __restrict__ q,
    const f16* __restrict__ k,
    const f16* __restrict__ vt,
    float* __restrict__ out)
{
    __shared__ __align__(16) f16 Kl[2][64 * 128];   // 32768 B, K dbuf, swizzled

    const int tid  = threadIdx.x;
    const int wave = tid >> 6;
    const int lane = tid & 63;
    const int col  = lane & 15;
    const int quad = lane >> 4;
    const int c7   = col & 7;
    const int b    = blockIdx.x;            // XCD = b % 8
    const int q0   = blockIdx.y * BQ;
    const int NC   = T_ / BK;

    // staging lane constants (K only)
    const int klr = lane >> 4;          // K: row-in-slab 0..3
    const int kph = (lane & 15) & 8;    // K: granule pos high bit
    const int kpl = lane & 7;           // K: granule pos low bits

    // V direct-load row base: lane reads vt row (ht*16+col), granule quad (+4)
    const f16* vrow0 = vt + ((size_t)(b * H_ + col)) * T_ + quad * 8;

    // Q fragments (reused NC chunks) — B-operand layout [n=lane&15][k=quad*8+j]
    half8 qf[2][4];
    #pragma unroll
    for (int qt = 0; qt < 2; ++qt) {
        const f16* qrow =
            q + ((size_t)(b * T_ + q0 + wave * 32 + qt * 16 + col)) * H_ + quad * 8;
        #pragma unroll
        for (int ks = 0; ks < 4; ++ks)
            qf[qt][ks] = *(const half8*)(qrow + ks * 32);
    }

    floatx4 o[2][8];   // Ot accum: lane holds q=qt*16+col, h=ht*16+quad*4+r
    #pragma unroll
    for (int qt = 0; qt < 2; ++qt)
        #pragma unroll
        for (int ht = 0; ht < 8; ++ht) { o[qt][ht][0]=0.f; o[qt][ht][1]=0.f; o[qt][ht][2]=0.f; o[qt][ht][3]=0.f; }
    float lsum[2] = {0.f, 0.f};

    #define ISSUE_K(S0, BUF)                                                      \
        do { _Pragma("unroll")                                                    \
            for (int it = 0; it < 4; ++it) {                                      \
                int slab = wave * 4 + it;                                         \
                int r7   = ((slab & 1) * 4 + klr);                                \
                int g    = kph | (kpl ^ r7);                                      \
                async_cp16(k + ((size_t)(b * T_ + (S0) + slab * 4 + klr)) * H_ + g * 8, \
                           (void*)&Kl[BUF][slab * 512]);                          \
            }                                                                     \
        } while (0)

    ISSUE_K(0, 0);     // prologue: chunk 0 (one-time startup stall)

    for (int ci2 = 0; ci2 < NC; ci2 += 2) {
        #pragma unroll
        for (int sub = 0; sub < 2; ++sub) {
            const int ci  = ci2 + sub;
            const int buf = sub;                 // compile-time LDS buffer index
            const int s0c = ci * BK;
            // ONE barrier per chunk: implicit vmcnt(0) drains K(ci) (issued a
            // full chunk ago); prior chunk's reads of Kl[buf] are done.
            __syncthreads();

            // ---- va0: V tile-pair 0 direct from global (L2-hot), 8x b128;
            //      completes under QK cluster
            half8 va0[8];
            #pragma unroll
            for (int ht = 0; ht < 8; ++ht)
                va0[ht] = *(const half8*)(vrow0 + (size_t)ht * 16 * T_ + s0c);

            if (ci + 1 < NC) ISSUE_K(s0c + BK, buf ^ 1);   // full-chunk cover

            // ---- K fragment preload: 16x ds_read_b128, addresses loop-invariant
            half8 kf[4][4];
            #pragma unroll
            for (int st = 0; st < 4; ++st)
                #pragma unroll
                for (int ks = 0; ks < 4; ++ks) {
                    int p = ((ks & 2) << 2) | ((((ks & 1) * 4) + quad) ^ c7);
                    kf[st][ks] = *(const half8*)&Kl[buf][(st * 16 + col) * 128 + p * 8];
                }

            // ---- QK: pure-register 32-MFMA cluster (unified)
            floatx4 s[2][4];
            __builtin_amdgcn_s_setprio(1);
            #pragma unroll
            for (int st = 0; st < 4; ++st) {
                s[0][st] = floatx4{0.f, 0.f, 0.f, 0.f};
                s[1][st] = floatx4{0.f, 0.f, 0.f, 0.f};
                #pragma unroll
                for (int ks = 0; ks < 4; ++ks) {
                    s[0][st] = __builtin_amdgcn_mfma_f32_16x16x32_f16(kf[st][ks], qf[0][ks], s[0][st], 0, 0, 0);
                    s[1][st] = __builtin_amdgcn_mfma_f32_16x16x32_f16(kf[st][ks], qf[1][ks], s[1][st], 0, 0, 0);
                }
            }
            __builtin_amdgcn_s_setprio(0);

            // ---- va1: V tile-pair 1, completes under softmax
            half8 va1[8];
            #pragma unroll
            for (int ht = 0; ht < 8; ++ht)
                va1[ht] = *(const half8*)(vrow0 + (size_t)ht * 16 * T_ + s0c + 32);

            // ---- softmax: single VALU phase (q pre-scaled by scale*log2e)
            half4 pf[2][4];
            #pragma unroll
            for (int st = 0; st < 4; ++st)
                #pragma unroll
                for (int qt = 0; qt < 2; ++qt) {
                    float p0 = fexp2(s[qt][st][0]), p1 = fexp2(s[qt][st][1]);
                    float p2 = fexp2(s[qt][st][2]), p3 = fexp2(s[qt][st][3]);
                    lsum[qt] += (p0 + p1) + (p2 + p3);
                    pf[qt][st] = __builtin_shufflevector(pkrtz(p0, p1), pkrtz(p2, p3), 0, 1, 2, 3);
                }

            // ---- PV: A-operand = the lane's own direct-loaded V granules
            #pragma unroll
            for (int sp32 = 0; sp32 < 2; ++sp32) {
                half8 p8[2];
                #pragma unroll
                for (int qt = 0; qt < 2; ++qt)
                    p8[qt] = __builtin_shufflevector(pf[qt][sp32 * 2], pf[qt][sp32 * 2 + 1],
                                                     0, 1, 2, 3, 4, 5, 6, 7);
                __builtin_amdgcn_s_setprio(1);
                #pragma unroll
                for (int ht = 0; ht < 8; ++ht) {
                    half8 va = sp32 ? va1[ht] : va0[ht];
                    o[0][ht] = __builtin_amdgcn_mfma_f32_16x16x32_f16(va, p8[0], o[0][ht], 0, 0, 0);
                    o[1][ht] = __builtin_amdgcn_mfma_f32_16x16x32_f16(va, p8[1], o[1][ht], 0, 0, 0);
                }
                __builtin_amdgcn_s_setprio(0);
            }
        }
    }
    #undef ISSUE_K

    // epilogue: reduce lsum across quads, normalize, store final fp32
    #pragma unroll
    for (int qt = 0; qt < 2; ++qt) {
        float l = lsum[qt];
        l += __shfl_xor(l, 16);
        l += __shfl_xor(l, 32);
        float rinv = 1.0f / l;
        int qrow = q0 + wave * 32 + qt * 16 + col;
        float* orow = out + ((size_t)(b * T_ + qrow)) * H_;
        #pragma unroll
        for (int ht = 0; ht < 8; ++ht) {
            float4 st4 = {o[qt][ht][0] * rinv, o[qt][ht][1] * rinv,
                          o[qt][ht][2] * rinv, o[qt][ht][3] * rinv};
            *(float4*)&orow[ht * 16 + quad * 4] = st4;
        }
    }
}

extern "C" void kernel_launch(void* const* d_in, const int* in_sizes, int n_in,
                              void* d_out, int out_size, void* d_ws, size_t ws_size,
                              hipStream_t stream)
{
    const float* x  = (const float*)d_in[0];
    const float* Wk = (const float*)d_in[1];
    const float* Wq = (const float*)d_in[2];
    const float* Wv = (const float*)d_in[3];
    float* out = (float*)d_out;

    const size_t elems = (size_t)B_ * T_ * H_;            // 8.4M elements
    f16* qb  = (f16*)d_ws;                                // f16 q   [B][T][H]    16.8 MB
    f16* kb  = qb + elems;                                // f16 k   [B][T][H]    16.8 MB
    f16* vtb = kb + elems;                                // f16 v^T [B][H][T']   16.8 MB (permuted t)
    f16* wtb = vtb + elems;                               // f16 W^T [3][H][C]    48 KB

    wprep_kernel<<<dim3(3, 16), dim3(256), 0, stream>>>(Wk, Wq, Wv, wtb);
    proj_kernel<<<dim3(B_ * 64), dim3(256), 0, stream>>>(x, wtb, qb, kb, vtb);
    attn_kernel<<<dim3(B_, T_ / BQ), dim3(256), 0, stream>>>(qb, kb, vtb, out);
}

// Round 11
// 234.860 us; speedup vs baseline: 1.5410x; 1.5410x over previous
//
#include <hip/hip_runtime.h>
#include <stdint.h>

#define B_ 16
#define T_ 4096
#define C_ 64
#define H_ 128
#define BQ 128
#define BK 64

typedef _Float16 f16;
typedef __attribute__((ext_vector_type(8))) _Float16 half8;   // 4 VGPRs (16x16x32 A/B)
typedef __attribute__((ext_vector_type(4))) _Float16 half4;   // 2 VGPRs
typedef __attribute__((ext_vector_type(2))) _Float16 half2v;  // 1 VGPR
typedef __attribute__((ext_vector_type(4))) float   floatx4;  // MFMA C/D frag

__device__ __forceinline__ f16 f2h(float f) { return (f16)f; }

__device__ __forceinline__ float fexp2(float x) {
#if __has_builtin(__builtin_amdgcn_exp2f)
    return __builtin_amdgcn_exp2f(x);
#else
    return exp2f(x);
#endif
}

// packed f32x2 -> f16x2 (single v_cvt_pkrtz_f16_f32)
__device__ __forceinline__ half2v pkrtz(float a, float b) {
    return __builtin_bit_cast(half2v, __builtin_amdgcn_cvt_pkrtz(a, b));
}

// async global->LDS, 16 B per lane, dest = wave-uniform base + lane*16
__device__ __forceinline__ void async_cp16(const void* g, void* l) {
    __builtin_amdgcn_global_load_lds(
        (const __attribute__((address_space(1))) unsigned int*)g,
        (__attribute__((address_space(3))) unsigned int*)l, 16, 0, 0);
}

// q is pre-scaled by scale*log2(e) at projection time (attn does exp2(S) raw)
#define QSCALE 0.18033688011112042f   // 0.125 * log2(e)

// ---------------------------------------------------------------------------
// W prep: Wk/Wq/Wv fp32 [C][H] -> f16 W^T [m][H][C], done ONCE.
// Grid (3 m, 16 h-groups) = 48 blocks.
// ---------------------------------------------------------------------------
__global__ __launch_bounds__(256) void wprep_kernel(
    const float* __restrict__ Wk, const float* __restrict__ Wq,
    const float* __restrict__ Wv, f16* __restrict__ wt)
{
    const int m  = blockIdx.x;
    const int hg = blockIdx.y;
    const float* W = (m == 0) ? Wk : (m == 1) ? Wq : Wv;
    f16* o = wt + m * (C_ * H_);
    #pragma unroll
    for (int it = 0; it < 2; ++it) {
        int idx = hg * 512 + it * 256 + threadIdx.x;  // idx = h*64 + c
        int h = idx >> 6, c = idx & 63;
        o[idx] = f2h(W[c * H_ + h]);                  // strided 4B reads, L2-resident
    }
}

// ---------------------------------------------------------------------------
// MFMA projections: q,k -> f16 [B][T][H]; v -> f16 vt[B][H][T'].
// vt's t-order is PERMUTED within each 64-t chunk so attn's PV operand is one
// contiguous 16-B granule per lane:
//   position p = 8g+u  holds  t-offset k = 32*g2 | 16*u2 | 8*g1 | 4*g0 | u1u0
// (g = granule 0..7, u = 0..7). Then granule g = 4*sp32 + quad is exactly the
// 8 k-values lane(quad) needs for PV tile-pair sp32 -> single ds_read_b128.
// q (m==1) is multiplied by QSCALE before the f16 store.
// ---------------------------------------------------------------------------
#define QKS 132   // q/k scratch stride (f16)
#define VTS 72    // vt scratch stride (f16)

__global__ __launch_bounds__(256) void proj_kernel(
    const float* __restrict__ x, const f16* __restrict__ wt,
    f16* __restrict__ qo, f16* __restrict__ ko, f16* __restrict__ vto)
{
    __shared__ __align__(16) char smem[20480];
    f16* Sw  = (f16*)smem;                          // per-wave [16][QKS] transpose scratch
    f16* vtl = (f16*)smem;                          // [128 h][VTS]  18432 B (aliases Sw)

    const int tid  = threadIdx.x;
    const int wave = tid >> 6;
    const int lane = tid & 63;
    const int col  = lane & 15;
    const int quad = lane >> 4;
    const int b    = blockIdx.x >> 6;
    const int t0   = (blockIdx.x & 63) * 64;

    // A-fragments: x rows t0+wave*16+col, K=64 in 2 ks-steps (fp32 -> f16)
    half8 ax[2];
    {
        const float* xr = x + ((size_t)(b * T_ + t0 + wave * 16 + col)) * C_ + quad * 8;
        #pragma unroll
        for (int ks = 0; ks < 2; ++ks) {
            float4 a0 = *(const float4*)(xr + ks * 32);
            float4 a1 = *(const float4*)(xr + ks * 32 + 4);
            ax[ks] = half8{f2h(a0.x), f2h(a0.y), f2h(a0.z), f2h(a0.w),
                           f2h(a1.x), f2h(a1.y), f2h(a1.z), f2h(a1.w)};
        }
    }

    #pragma unroll
    for (int m = 0; m < 3; ++m) {
        const f16* Wm = wt + m * (C_ * H_);
        const float sc = (m == 1) ? QSCALE : 1.0f;   // fold attn scale into q

        floatx4 acc[8];
        #pragma unroll
        for (int nt = 0; nt < 8; ++nt) { acc[nt][0]=0.f; acc[nt][1]=0.f; acc[nt][2]=0.f; acc[nt][3]=0.f; }
        #pragma unroll
        for (int nt = 0; nt < 8; ++nt)
            #pragma unroll
            for (int ks = 0; ks < 2; ++ks) {
                half8 bf = *(const half8*)(Wm + (nt * 16 + col) * C_ + ks * 32 + quad * 8);
                acc[nt] = __builtin_amdgcn_mfma_f32_16x16x32_f16(ax[ks], bf, acc[nt], 0, 0, 0);
            }

        if (m < 2) {
            // wave-private scratch: DS ops of one wave execute in order -> no barrier
            f16* S = Sw + wave * 16 * QKS;
            #pragma unroll
            for (int nt = 0; nt < 8; ++nt)
                #pragma unroll
                for (int r = 0; r < 4; ++r)
                    S[(quad * 4 + r) * QKS + nt * 16 + col] = f2h(acc[nt][r] * sc);
            f16* o = (m == 0) ? ko : qo;
            int rw = lane >> 2;
            #pragma unroll
            for (int p = 0; p < 4; ++p) {
                int ck = (lane & 3) + p * 4;
                half8 d = *(const half8*)&S[rw * QKS + ck * 8];
                *(half8*)(o + ((size_t)(b * T_ + t0 + wave * 16 + rw)) * H_ + ck * 8) = d;
            }
        } else {
            __syncthreads();   // all waves' q-scratch reads done; vtl spans whole smem
            #pragma unroll
            for (int nt = 0; nt < 8; ++nt)
                #pragma unroll
                for (int r = 0; r < 4; ++r)
                    vtl[(nt * 16 + col) * VTS + wave * 16 + quad * 4 + r] = f2h(acc[nt][r]);
            __syncthreads();
            // permuted store: source granule gs (t = 8gs..8gs+7) splits into two
            // 8-B halves at positions (G, u4) and (G+1, u4), G = 4*gs2 + 2*gs0,
            // u4 = 4*gs1  (see layout comment above).
            int h  = tid >> 1;
            int sg = (tid & 1) * 32;
            f16* drow = vto + ((size_t)(b * H_ + h)) * T_ + t0;
            const int4* src = (const int4*)&vtl[h * VTS + sg];
            #pragma unroll
            for (int i = 0; i < 4; ++i) {
                int gs = (sg >> 3) + i;
                int G  = ((gs >> 2) << 2) | ((gs & 1) << 1);
                int u4 = ((gs >> 1) & 1) << 2;
                int4 v = src[i];
                *(int2*)(drow + (G + 0) * 8 + u4) = make_int2(v.x, v.y);
                *(int2*)(drow + (G + 1) * 8 + u4) = make_int2(v.z, v.w);
            }
        }
    }
}

// ---------------------------------------------------------------------------
// Flash attention. Grid (16 b, 32 q): x = b -> all 32 q-blocks of a batch on
// one XCD, K/V served from its L2 (FETCH 139->24.6 MB, round 9).
// K and V BOTH LDS-staged (round 10 proved V-from-global saturates the L1
// path: per-lane loads span 16 cache lines -> attn 141->285 µs) and BOTH
// double-buffered: ONE barrier per chunk, full-chunk staging cover.
// SPLIT-SOFTMAX schedule (this round's change): softmax st0,1 -> PV sp32=0
// -> softmax st2,3 -> PV sp32=1. PV(sp0) depends only on pf[.][0..1], so the
// second softmax half can execute in the MFMA shadow of the first PV cluster
// (own-wave VALU/MFMA overlap instead of one long VALU phase).
// Chunk loop unrolled x2 so the LDS buffer index is compile-time.
// lsum completes in-kernel -> normalize in epilogue, single output pass.
// ---------------------------------------------------------------------------
__global__ __launch_bounds__(256, 2) void attn_kernel(
    const f16* __restrict__ q,
    const f16* __restrict__ k,
    const f16* __restrict__ vt,
    float* __restrict__ out)
{
    __shared__ __align__(16) f16 Kl[2][64 * 128];   // 32768 B, swizzled granules
    __shared__ __align__(16) f16 Vtl[2][128 * 64];  // 32768 B, permuted granules

    const int tid  = threadIdx.x;
    const int wave = tid >> 6;
    const int lane = tid & 63;
    const int col  = lane & 15;
    const int quad = lane >> 4;
    const int c7   = col & 7;
    const int b    = blockIdx.x;            // XCD = b % 8
    const int q0   = blockIdx.y * BQ;
    const int NC   = T_ / BK;

    // staging lane constants
    const int klr = lane >> 4;          // K: row-in-slab 0..3
    const int kph = (lane & 15) & 8;    // K: granule pos high bit
    const int kpl = lane & 7;           // K: granule pos low bits
    const int vrow = lane >> 3;         // V: row-in-call 0..7
    const int vswz = (lane & 7) ^ vrow; // V: swizzled source granule

    // Q fragments (reused NC chunks) — B-operand layout [n=lane&15][k=quad*8+j]
    half8 qf[2][4];
    #pragma unroll
    for (int qt = 0; qt < 2; ++qt) {
        const f16* qrow =
            q + ((size_t)(b * T_ + q0 + wave * 32 + qt * 16 + col)) * H_ + quad * 8;
        #pragma unroll
        for (int ks = 0; ks < 4; ++ks)
            qf[qt][ks] = *(const half8*)(qrow + ks * 32);
    }

    floatx4 o[2][8];   // Ot accum: lane holds q=qt*16+col, h=ht*16+quad*4+r
    #pragma unroll
    for (int qt = 0; qt < 2; ++qt)
        #pragma unroll
        for (int ht = 0; ht < 8; ++ht) { o[qt][ht][0]=0.f; o[qt][ht][1]=0.f; o[qt][ht][2]=0.f; o[qt][ht][3]=0.f; }
    float lsum[2] = {0.f, 0.f};

    #define ISSUE_K(S0, BUF)                                                      \
        do { _Pragma("unroll")                                                    \
            for (int it = 0; it < 4; ++it) {                                      \
                int slab = wave * 4 + it;                                         \
                int r7   = ((slab & 1) * 4 + klr);                                \
                int g    = kph | (kpl ^ r7);                                      \
                async_cp16(k + ((size_t)(b * T_ + (S0) + slab * 4 + klr)) * H_ + g * 8, \
                           (void*)&Kl[BUF][slab * 512]);                          \
            }                                                                     \
        } while (0)

    #define ISSUE_VT(S0, BUF)                                                     \
        do { _Pragma("unroll")                                                    \
            for (int it = 0; it < 4; ++it) {                                      \
                int hbase = wave * 32 + it * 8;                                   \
                async_cp16(vt + ((size_t)(b * H_ + hbase + vrow)) * T_ + (S0) + vswz * 8, \
                           (void*)&Vtl[BUF][hbase * 64]);                         \
            }                                                                     \
        } while (0)

    // softmax of one st (both qt): exp2 + lsum + f16 pack
    #define SMAX(st)                                                              \
        do { _Pragma("unroll")                                                    \
            for (int qt = 0; qt < 2; ++qt) {                                      \
                float p0 = fexp2(s[qt][st][0]), p1 = fexp2(s[qt][st][1]);         \
                float p2 = fexp2(s[qt][st][2]), p3 = fexp2(s[qt][st][3]);         \
                lsum[qt] += (p0 + p1) + (p2 + p3);                                \
                pf[qt][st] = __builtin_shufflevector(pkrtz(p0, p1), pkrtz(p2, p3), 0, 1, 2, 3); \
            }                                                                     \
        } while (0)

    // PV cluster for one tile-pair sp32 (V granule read + 16 MFMA)
    #define PVHALF(SP, BUF)                                                       \
        do {                                                                      \
            half8 p8[2];                                                          \
            _Pragma("unroll")                                                     \
            for (int qt = 0; qt < 2; ++qt)                                        \
                p8[qt] = __builtin_shufflevector(pf[qt][(SP) * 2], pf[qt][(SP) * 2 + 1], \
                                                 0, 1, 2, 3, 4, 5, 6, 7);         \
            const int gl8 = (((SP) * 4 + quad) ^ c7) * 8;                         \
            half8 va[8];                                                          \
            _Pragma("unroll")                                                     \
            for (int ht = 0; ht < 8; ++ht)                                        \
                va[ht] = *(const half8*)&Vtl[BUF][(ht * 16 + col) * 64 + gl8];    \
            __builtin_amdgcn_s_setprio(1);                                        \
            _Pragma("unroll")                                                     \
            for (int ht = 0; ht < 8; ++ht) {                                      \
                o[0][ht] = __builtin_amdgcn_mfma_f32_16x16x32_f16(va[ht], p8[0], o[0][ht], 0, 0, 0); \
                o[1][ht] = __builtin_amdgcn_mfma_f32_16x16x32_f16(va[ht], p8[1], o[1][ht], 0, 0, 0); \
            }                                                                     \
            __builtin_amdgcn_s_setprio(0);                                        \
        } while (0)

    ISSUE_K(0, 0);     // prologue: chunk 0 (one-time startup stall)
    ISSUE_VT(0, 0);

    for (int ci2 = 0; ci2 < NC; ci2 += 2) {
        #pragma unroll
        for (int sub = 0; sub < 2; ++sub) {
            const int ci  = ci2 + sub;
            const int buf = sub;                 // compile-time LDS buffer index
            const int s0c = ci * BK;
            // ONE barrier per chunk: implicit vmcnt(0) drains K(ci),V(ci)
            // (issued a full chunk ago); chunk ci-1's reads of buf^1 are done.
            __syncthreads();
            if (ci + 1 < NC) {
                ISSUE_K(s0c + BK, buf ^ 1);      // full-chunk latency cover
                ISSUE_VT(s0c + BK, buf ^ 1);
            }

            // ---- K fragment preload: 16x ds_read_b128, addresses loop-invariant
            half8 kf[4][4];
            #pragma unroll
            for (int st = 0; st < 4; ++st)
                #pragma unroll
                for (int ks = 0; ks < 4; ++ks) {
                    int p = ((ks & 2) << 2) | ((((ks & 1) * 4) + quad) ^ c7);
                    kf[st][ks] = *(const half8*)&Kl[buf][(st * 16 + col) * 128 + p * 8];
                }

            // ---- QK: pure-register 32-MFMA cluster (unified)
            floatx4 s[2][4];
            __builtin_amdgcn_s_setprio(1);
            #pragma unroll
            for (int st = 0; st < 4; ++st) {
                s[0][st] = floatx4{0.f, 0.f, 0.f, 0.f};
                s[1][st] = floatx4{0.f, 0.f, 0.f, 0.f};
                #pragma unroll
                for (int ks = 0; ks < 4; ++ks) {
                    s[0][st] = __builtin_amdgcn_mfma_f32_16x16x32_f16(kf[st][ks], qf[0][ks], s[0][st], 0, 0, 0);
                    s[1][st] = __builtin_amdgcn_mfma_f32_16x16x32_f16(kf[st][ks], qf[1][ks], s[1][st], 0, 0, 0);
                }
            }
            __builtin_amdgcn_s_setprio(0);

            // ---- split-softmax schedule: st0,1 -> PV(sp0); st2,3 hide under
            //      PV(sp0)'s MFMA cluster; then PV(sp1).
            half4 pf[2][4];
            SMAX(0);
            SMAX(1);
            PVHALF(0, buf);
            SMAX(2);
            SMAX(3);
            PVHALF(1, buf);
        }
    }
    #undef ISSUE_K
    #undef ISSUE_VT
    #undef SMAX
    #undef PVHALF

    // epilogue: reduce lsum across quads, normalize, store final fp32
    #pragma unroll
    for (int qt = 0; qt < 2; ++qt) {
        float l = lsum[qt];
        l += __shfl_xor(l, 16);
        l += __shfl_xor(l, 32);
        float rinv = 1.0f / l;
        int qrow = q0 + wave * 32 + qt * 16 + col;
        float* orow = out + ((size_t)(b * T_ + qrow)) * H_;
        #pragma unroll
        for (int ht = 0; ht < 8; ++ht) {
            float4 st4 = {o[qt][ht][0] * rinv, o[qt][ht][1] * rinv,
                          o[qt][ht][2] * rinv, o[qt][ht][3] * rinv};
            *(float4*)&orow[ht * 16 + quad * 4] = st4;
        }
    }
}

extern "C" void kernel_launch(void* const* d_in, const int* in_sizes, int n_in,
                              void* d_out, int out_size, void* d_ws, size_t ws_size,
                              hipStream_t stream)
{
    const float* x  = (const float*)d_in[0];
    const float* Wk = (const float*)d_in[1];
    const float* Wq = (const float*)d_in[2];
    const float* Wv = (const float*)d_in[3];
    float* out = (float*)d_out;

    const size_t elems = (size_t)B_ * T_ * H_;            // 8.4M elements
    f16* qb  = (f16*)d_ws;                                // f16 q   [B][T][H]    16.8 MB
    f16* kb  = qb + elems;                                // f16 k   [B][T][H]    16.8 MB
    f16* vtb = kb + elems;                                // f16 v^T [B][H][T']   16.8 MB (permuted t)
    f16* wtb = vtb + elems;                               // f16 W^T [3][H][C]    48 KB

    wprep_kernel<<<dim3(3, 16), dim3(256), 0, stream>>>(Wk, Wq, Wv, wtb);
    proj_kernel<<<dim3(B_ * 64), dim3(256), 0, stream>>>(x, wtb, qb, kb, vtb);
    attn_kernel<<<dim3(B_, T_ / BQ), dim3(256), 0, stream>>>(qb, kb, vtb, out);
}